// Round 8
// baseline (627.222 us; speedup 1.0000x reference)
//
#include <hip/hip_runtime.h>
#include <hip/hip_bf16.h>
#include <math.h>

// GPT-OSS MoE block. Split-bf16 MFMA (A hi/lo, B hi-RNE, 2 passes).
// R8: (1) LDS double-buffer, ONE barrier per K-step (was 2) — attacks
// barrier-drain lockstep; (2) DAG 6->4 dispatches: prefix inlined,
// combine fused into mlp2 via atomicAdd, out pre-init to x in rms_gate.
// GEMM core math identical to R7 (passed, absmax 0.015625).
// B=512 H=1024 I=1024 E=32 K=4.
//
// ws (floats): t[512*1024] | a[2048*1024] | tok[32*512](int) |
//              wte[32*512] | cnt[32](int)

#define NB   512
#define NH   1024
#define NI   1024
#define NE   32
#define NK   4
#define N2I  2048
#define CAP  512
#define PADK 40   // 80B row stride: 16B-aligned, 2-way (free) bank aliasing

static constexpr float EPS   = 1e-5f;
static constexpr float ALPHA = 1.702f;
static constexpr float LIMIT = 7.0f;

typedef short bf16x8 __attribute__((ext_vector_type(8)));
typedef float f32x4  __attribute__((ext_vector_type(4)));

__device__ __forceinline__ short hi16(float x) {
    return (short)(__float_as_uint(x) >> 16);
}
__device__ __forceinline__ short lo16(float x) {
    unsigned hb = __float_as_uint(x) & 0xFFFF0000u;
    float r = x - __uint_as_float(hb);
    return (short)(__float_as_uint(r) >> 16);
}
__device__ __forceinline__ short rne16(float x) {
    unsigned u = __float_as_uint(x);
    return (short)((u + 0x7FFFu + ((u >> 16) & 1u)) >> 16);
}
__device__ __forceinline__ void cvtsplit8(float4 v0, float4 v1,
                                          bf16x8& hh, bf16x8& ll) {
    float f[8] = {v0.x, v0.y, v0.z, v0.w, v1.x, v1.y, v1.z, v1.w};
#pragma unroll
    for (int i = 0; i < 8; i++) { hh[i] = hi16(f[i]); ll[i] = lo16(f[i]); }
}
__device__ __forceinline__ void cvtrne8(float4 v0, float4 v1, bf16x8& hh) {
    float f[8] = {v0.x, v0.y, v0.z, v0.w, v1.x, v1.y, v1.z, v1.w};
#pragma unroll
    for (int i = 0; i < 8; i++) hh[i] = rne16(f[i]);
}

// ------------------------------- rmsnorm + gate + top4 + route + out=x
__global__ __launch_bounds__(256) void k_rms_gate(
    const float* __restrict__ x, const float* __restrict__ scale,
    const float* __restrict__ gw, const float* __restrict__ gb,
    float* __restrict__ t, int* __restrict__ cnt,
    int* __restrict__ tok, float* __restrict__ wte,
    float* __restrict__ out) {
    __shared__ float sh_t[NH];
    __shared__ float sh_red[4];
    __shared__ float sh_g[NE];
    const int b = blockIdx.x, tid = threadIdx.x;
    const int lane = tid & 63, wid = tid >> 6;

    float4 xv = reinterpret_cast<const float4*>(x + (size_t)b * NH)[tid];
    reinterpret_cast<float4*>(out + (size_t)b * NH)[tid] = xv;   // out = x
    float ss = xv.x * xv.x + xv.y * xv.y + xv.z * xv.z + xv.w * xv.w;
#pragma unroll
    for (int o = 32; o >= 1; o >>= 1) ss += __shfl_down(ss, o);
    if (lane == 0) sh_red[wid] = ss;
    __syncthreads();
    const float tot = sh_red[0] + sh_red[1] + sh_red[2] + sh_red[3];
    const float r = rsqrtf(tot * (1.0f / NH) + EPS);
    float4 sv = reinterpret_cast<const float4*>(scale)[tid];
    float4 tv;
    tv.x = xv.x * r * sv.x; tv.y = xv.y * r * sv.y;
    tv.z = xv.z * r * sv.z; tv.w = xv.w * r * sv.w;
    reinterpret_cast<float4*>(sh_t)[tid] = tv;
    reinterpret_cast<float4*>(t + (size_t)b * NH)[tid] = tv;
    __syncthreads();

#pragma unroll
    for (int q = 0; q < 8; q++) {
        const int e = wid * 8 + q;
        const float* __restrict__ w = gw + (size_t)e * NH;
        float p = 0.f;
#pragma unroll
        for (int i = 0; i < 16; i++) { int k = lane + 64 * i; p += sh_t[k] * w[k]; }
#pragma unroll
        for (int o = 32; o >= 1; o >>= 1) p += __shfl_down(p, o);
        if (lane == 0) sh_g[e] = p + gb[e];
    }
    __syncthreads();

    if (tid == 0) {
        float gv[NE];
#pragma unroll
        for (int e = 0; e < NE; e++) gv[e] = sh_g[e];
        float vals[NK]; int ids[NK];
#pragma unroll
        for (int k = 0; k < NK; k++) {          // strict > keeps lowest index
            int bi = 0; float bv = gv[0];
            for (int e = 1; e < NE; e++) if (gv[e] > bv) { bv = gv[e]; bi = e; }
            vals[k] = bv; ids[k] = bi; gv[bi] = -1e30f;
        }
        const float m = vals[0];
        float s = 0.f, wv[NK];
#pragma unroll
        for (int k = 0; k < NK; k++) { wv[k] = __expf(vals[k] - m); s += wv[k]; }
        const float inv = 1.f / s;
#pragma unroll
        for (int k = 0; k < NK; k++) {
            const int e = ids[k];
            const int pos = atomicAdd(&cnt[e], 1);
            tok[e * CAP + pos] = b;
            wte[e * CAP + pos] = wv[k] * inv;
        }
    }
}

// load one reg set at float-offset k (A granules + B granules)
#define LOADBUF(Aa, Ab, Ac, Ad, Ba, Bb, Bc, Bd, k)                           \
    do {                                                                     \
        Aa = *(const float4*)(asrc + (k));      Ab = *(const float4*)(asrc + (k) + 4);  \
        Ac = *(const float4*)(asrc + (k) + 16); Ad = *(const float4*)(asrc + (k) + 20); \
        Ba = *(const float4*)(bsrc + (k));      Bb = *(const float4*)(bsrc + (k) + 4);  \
        Bc = *(const float4*)(bsrc + (k) + 16); Bd = *(const float4*)(bsrc + (k) + 20); \
    } while (0)

// convert + store one reg set into LDS buffer S
#define CVT_STORE(S, Aa, Ab, Ac, Ad, Ba, Bb, Bc, Bd)                         \
    do {                                                                     \
        bf16x8 hh, ll;                                                       \
        cvtsplit8(Aa, Ab, hh, ll);                                           \
        if (zA) { hh = (bf16x8)(short)0; ll = (bf16x8)(short)0; }            \
        *(bf16x8*)&Ah[S][srow][sh8] = hh;  *(bf16x8*)&Al[S][srow][sh8] = ll; \
        cvtsplit8(Ac, Ad, hh, ll);                                           \
        if (zA) { hh = (bf16x8)(short)0; ll = (bf16x8)(short)0; }            \
        *(bf16x8*)&Ah[S][srow][sh8 + 16] = hh; *(bf16x8*)&Al[S][srow][sh8 + 16] = ll; \
        cvtrne8(Ba, Bb, hh);  *(bf16x8*)&Bh[S][srow][sh8] = hh;              \
        cvtrne8(Bc, Bd, hh);  *(bf16x8*)&Bh[S][srow][sh8 + 16] = hh;         \
    } while (0)

// MFMA from LDS buffer S: 12 b128 frag reads -> 32 mfma (AhBh + AlBh)
#define MFMA_PHASE(S)                                                        \
    do {                                                                     \
        bf16x8 ah[4], al[4], bh[4];                                          \
        _Pragma("unroll")                                                    \
        for (int m = 0; m < 4; m++) {                                        \
            const int r = wr * 64 + m * 16 + frow;                           \
            ah[m] = *(const bf16x8*)&Ah[S][r][fk];                           \
            al[m] = *(const bf16x8*)&Al[S][r][fk];                           \
        }                                                                    \
        _Pragma("unroll")                                                    \
        for (int n = 0; n < 4; n++) {                                        \
            const int c = wc * 64 + n * 16 + frow;                           \
            bh[n] = *(const bf16x8*)&Bh[S][c][fk];                           \
        }                                                                    \
        _Pragma("unroll")                                                    \
        for (int m = 0; m < 4; m++)                                          \
            _Pragma("unroll")                                                \
            for (int n = 0; n < 4; n++) {                                    \
                acc[m][n] = __builtin_amdgcn_mfma_f32_16x16x32_bf16(ah[m], bh[n], acc[m][n], 0, 0, 0); \
                acc[m][n] = __builtin_amdgcn_mfma_f32_16x16x32_bf16(al[m], bh[n], acc[m][n], 0, 0, 0); \
            }                                                                \
    } while (0)

// K-loop: chunk c (32 K) lives in LDS[c&1]; window c does
// { load chunk c+2 -> regs ; store chunk c+1 -> LDS[(c+1)&1] ; MFMA LDS[c&1] }
// with ONE barrier at window top (dbuf separation proof in comments above).
#define DBUF_KLOOP(KDIM)                                                     \
    LOADBUF(A0a, A0b, A0c, A0d, B0a, B0b, B0c, B0d, 0);                      \
    LOADBUF(A1a, A1b, A1c, A1d, B1a, B1b, B1c, B1d, 32);                     \
    CVT_STORE(0, A0a, A0b, A0c, A0d, B0a, B0b, B0c, B0d);                    \
    for (int k0 = 0; k0 < (KDIM); k0 += 64) {                                \
        __syncthreads();                                                     \
        if (k0 + 64 < (KDIM))                                                \
            LOADBUF(A0a, A0b, A0c, A0d, B0a, B0b, B0c, B0d, k0 + 64);        \
        CVT_STORE(1, A1a, A1b, A1c, A1d, B1a, B1b, B1c, B1d);                \
        MFMA_PHASE(0);                                                       \
        __syncthreads();                                                     \
        if (k0 + 96 < (KDIM))                                                \
            LOADBUF(A1a, A1b, A1c, A1d, B1a, B1b, B1c, B1d, k0 + 96);        \
        if (k0 + 64 < (KDIM))                                                \
            CVT_STORE(0, A0a, A0b, A0c, A0d, B0a, B0b, B0c, B0d);            \
        MFMA_PHASE(1);                                                       \
    }

// ------------------------------------------------- expert GEMM 1 + swiglu
// 256 thr / 4 waves (2Mx2N), block tile 128x128, wave tile 64x64, BK=32.
__global__ __launch_bounds__(256, 2) void k_mlp1(
    const float* __restrict__ t, const float* __restrict__ w1,
    const float* __restrict__ b1, const int* __restrict__ cnt,
    const int* __restrict__ tok, float* __restrict__ a) {
    const int e  = blockIdx.z;
    const int ne = cnt[e];
    const int m0 = blockIdx.y * 128;
    if (m0 >= ne) return;
    const int c0 = blockIdx.x * 128;
    const float* __restrict__ W = w1 + (size_t)e * N2I * NH + (size_t)c0 * NH;

    __shared__ short Ah[2][128][PADK], Al[2][128][PADK], Bh[2][128][PADK];
    __shared__ int   toks[128];

    const int tid = threadIdx.x;
    if (tid < 128) toks[tid] = (m0 + tid < ne) ? tok[e * CAP + m0 + tid] : -1;
    int slot0 = 0;                                  // inline prefix sum
    for (int q = 0; q < NE; q++) slot0 += (q < e) ? cnt[q] : 0;
    __syncthreads();

    const int lane = tid & 63;
    const int wid  = tid >> 6;
    const int wr = wid >> 1, wc = wid & 1;
    const int frow = lane & 15;
    const int fk   = (lane >> 4) * 8;
    const int srow = tid >> 1;
    const int sh8  = (tid & 1) * 8;

    f32x4 acc[4][4] = {};

    const int tka = toks[srow];
    const bool zA = (tka < 0);
    const float* __restrict__ asrc = t + (size_t)(zA ? 0 : tka) * NH + sh8;
    const float* __restrict__ bsrc = W + (size_t)srow * NH + sh8;

    float4 A0a, A0b, A0c, A0d, B0a, B0b, B0c, B0d;
    float4 A1a, A1b, A1c, A1d, B1a, B1b, B1c, B1d;
    DBUF_KLOOP(NH);

    // epilogue: bias + interleaved swiglu; adjacent lanes hold (glu,lin) pair
#pragma unroll
    for (int m = 0; m < 4; m++)
#pragma unroll
        for (int n = 0; n < 4; n++) {
            const int gcol = c0 + wc * 64 + n * 16 + frow;
            const float bias = b1[e * N2I + gcol];
            f32x4 v = acc[m][n];
#pragma unroll
            for (int j = 0; j < 4; j++) {
                const float h  = v[j] + bias;
                const float hp = __shfl_xor(h, 1);
                const int row = m0 + wr * 64 + m * 16 + (lane >> 4) * 4 + j;
                if (!(lane & 1) && row < ne) {
                    const float xg = fminf(h, LIMIT);
                    const float xl = fminf(fmaxf(hp, -LIMIT), LIMIT);
                    const float sg2 = 1.f / (1.f + __expf(-ALPHA * xg));
                    a[(size_t)(slot0 + row) * NI + (gcol >> 1)] = xg * sg2 * (xl + 1.f);
                }
            }
        }
}

// --------------------------------- expert GEMM 2 + weighted atomic combine
__global__ __launch_bounds__(256, 2) void k_mlp2(
    const float* __restrict__ a, const float* __restrict__ w2,
    const float* __restrict__ b2, const int* __restrict__ cnt,
    const int* __restrict__ tok, const float* __restrict__ wte,
    float* __restrict__ out) {
    const int e  = blockIdx.z;
    const int ne = cnt[e];
    const int m0 = blockIdx.y * 128;
    if (m0 >= ne) return;
    const int c0 = blockIdx.x * 128;
    const float* __restrict__ W = w2 + (size_t)e * NH * NI + (size_t)c0 * NI;

    __shared__ short Ah[2][128][PADK], Al[2][128][PADK], Bh[2][128][PADK];
    __shared__ int   toks[128];
    __shared__ float wts[128];

    const int tid = threadIdx.x;
    if (tid < 128) {
        const bool v = (m0 + tid < ne);
        toks[tid] = v ? tok[e * CAP + m0 + tid] : -1;
        wts[tid]  = v ? wte[e * CAP + m0 + tid] : 0.f;
    }
    int slot0 = 0;
    for (int q = 0; q < NE; q++) slot0 += (q < e) ? cnt[q] : 0;
    __syncthreads();

    const int lane = tid & 63;
    const int wid  = tid >> 6;
    const int wr = wid >> 1, wc = wid & 1;
    const int frow = lane & 15;
    const int fk   = (lane >> 4) * 8;
    const int srow = tid >> 1;
    const int sh8  = (tid & 1) * 8;

    f32x4 acc[4][4] = {};

    const bool zA = (m0 + srow >= ne);
    const float* __restrict__ asrc =
        a + (size_t)(zA ? 0 : (slot0 + m0 + srow)) * NI + sh8;
    const float* __restrict__ bsrc = W + (size_t)srow * NI + sh8;

    float4 A0a, A0b, A0c, A0d, B0a, B0b, B0c, B0d;
    float4 A1a, A1b, A1c, A1d, B1a, B1b, B1c, B1d;
    DBUF_KLOOP(NI);

    // epilogue: out[tok] += w * (acc + bias)   (out pre-initialized to x)
#pragma unroll
    for (int m = 0; m < 4; m++)
#pragma unroll
        for (int n = 0; n < 4; n++) {
            const int gcol = c0 + wc * 64 + n * 16 + frow;
            const float bias = b2[e * NH + gcol];
            f32x4 v = acc[m][n];
#pragma unroll
            for (int j = 0; j < 4; j++) {
                const int row = wr * 64 + m * 16 + (lane >> 4) * 4 + j;
                if (m0 + row < ne) {
                    const int   tk = toks[row];
                    const float wv = wts[row];
                    atomicAdd(&out[(size_t)tk * NH + gcol], wv * (v[j] + bias));
                }
            }
        }
}

// ---------------------------------------------------------------- launch
extern "C" void kernel_launch(void* const* d_in, const int* in_sizes, int n_in,
                              void* d_out, int out_size, void* d_ws, size_t ws_size,
                              hipStream_t stream) {
    const float* x     = (const float*)d_in[0];
    const float* scale = (const float*)d_in[1];
    const float* gw    = (const float*)d_in[2];
    const float* gb    = (const float*)d_in[3];
    const float* w1    = (const float*)d_in[4];
    const float* b1    = (const float*)d_in[5];
    const float* w2    = (const float*)d_in[6];
    const float* b2    = (const float*)d_in[7];
    float* out = (float*)d_out;

    float* t   = (float*)d_ws;                         // 512*1024
    float* a   = t + (size_t)NB * NH;                  // 2048*1024
    int*   tok = (int*)(a + (size_t)NB * NK * NI);     // 32*512
    float* wte = (float*)(tok + NE * CAP);             // 32*512
    int*   cnt = (int*)(wte + NE * CAP);               // 32

    hipMemsetAsync(cnt, 0, NE * sizeof(int), stream);
    k_rms_gate<<<NB, 256, 0, stream>>>(x, scale, gw, gb, t, cnt, tok, wte, out);
    k_mlp1<<<dim3(N2I / 128, NB / 128, NE), 256, 0, stream>>>(t, w1, b1, cnt, tok, a);
    k_mlp2<<<dim3(NH / 128, NB / 128, NE), 256, 0, stream>>>(a, w2, b2, cnt, tok, wte, out);
}